// Round 5
// baseline (366.082 us; speedup 1.0000x reference)
//
#include <hip/hip_runtime.h>
#include <hip/hip_cooperative_groups.h>
#include <stdint.h>

namespace cg = cooperative_groups;

// ---------- constants ----------
#define T_WIN   4096
#define DFULL   4096
#define DK      1024
#define GRID    256
#define LOG2_10000 13.287712379549449f

// ---------- workspace layout (bytes), non-overlapping ----------
static const size_t IDX_OFF  = 0;         // idxb [4096][16] uchar   = 65536
static const size_t FRQ_OFF  = 65536;     // freqt [2048] f          = 8192
static const size_t KQ_OFF   = 73728;     // kq    [4096] f          = 16384
static const size_t S_OFF    = 90112;     // s     [4096] f          = 16384
// ---- contiguous zero region: 10496 floats ----
static const size_t QP_OFF   = 106496;    // qp   [4][1024] f
static const size_t AXPE_OFF = 122880;    // axpe [4096] f
static const size_t W_OFF    = 139264;    // weight [144] f (pad 256)
static const size_t CTX_OFF  = 140288;    // ctx [1024] f
static const size_t OL_OFF   = 144384;    // ol  [1024] f
// end 148480

struct Par {
    const int* obs;
    const float* o_emb; const float* d_emb;
    const float* WQ; const float* WK; const float* WV; const float* WO;
    const float* Wo_pol; const float* bo_pol;
    const float* Wd_pol; const float* bd_pol;
    const float* Wv; const float* bv;
    unsigned char* idxb;
    float* freqt; float* kq; float* s;
    float* qp; float* axpe; float* weight; float* ctx; float* ol;
    float* out;
};

__global__ void __launch_bounds__(256) mega_k(Par p) {
    cg::grid_group grid = cg::this_grid();
    __shared__ __align__(16) float smem[11264];   // 44 KB, reused per phase
    int b = blockIdx.x, tid = threadIdx.x;
    int wave = tid >> 6, lane = tid & 63;

    // ---------------- P0: idx extraction + zero + freq ----------------
    {
        int g = b * 256 + tid;                    // obs row = t*16 + pl*2 + which
        const int* r = p.obs + (size_t)g * 9;
        int id = 0;
        #pragma unroll
        for (int j = 1; j < 9; ++j) id += j * r[j];
        int t = g >> 4, pl = (g >> 1) & 7, which = g & 1;
        p.idxb[t * 16 + which * 8 + pl] = (unsigned char)id;
        if (b == 1)
            for (int i = tid; i < 10496; i += 256) p.qp[i] = 0.0f;  // qp..ol contiguous
        if (b == 2)
            for (int i = tid; i < 2048; i += 256)
                p.freqt[i] = exp2f(-((float)(2 * i) * (1.0f / 4096.0f)) * LOG2_10000);
    }
    grid.sync();

    // ---------------- P1: q partials (block b = k-chunk of 16 rows) ----------------
    {
        int kb = b * 16;
        int pl = kb >> 9, rr = kb & 511;
        const float* tab; int r0, which;
        if (rr < 256) { tab = p.o_emb; r0 = rr;       which = 0; }
        else          { tab = p.d_emb; r0 = rr - 256; which = 1; }
        if (tid < 16) {
            int row = 65520 + pl * 2 + which;     // t = 4095 rows
            const int* r = p.obs + (size_t)row * 9;
            int id = 0;
            #pragma unroll
            for (int j = 1; j < 9; ++j) id += j * r[j];
            int c = kb + tid;
            float f = exp2f(-((float)(c & ~1) * (1.0f / 4096.0f)) * LOG2_10000);
            float sv, cv;
            __sincosf(4095.0f * f, &sv, &cv);
            smem[tid] = tab[id * 256 + r0 + tid] * 16.0f + ((c & 1) ? cv : sv);
        }
        __syncthreads();
        const float4* W4 = (const float4*)p.WQ;
        float4 acc = {0.f, 0.f, 0.f, 0.f};
        #pragma unroll
        for (int k = 0; k < 16; ++k) {
            float xv = smem[k];
            float4 w = W4[(size_t)(kb + k) * 256 + tid];
            acc.x += xv * w.x; acc.y += xv * w.y;
            acc.z += xv * w.z; acc.w += xv * w.w;
        }
        float* dst = p.qp + (b >> 6) * 1024 + tid * 4;
        atomicAdd(dst + 0, acc.x);
        atomicAdd(dst + 1, acc.y);
        atomicAdd(dst + 2, acc.z);
        atomicAdd(dst + 3, acc.w);
    }
    grid.sync();

    // ---------------- P2: kq[c] = (WK[c]·q)/32, 16 rows per block ----------------
    {
        float4* qls = (float4*)smem;
        const float4* p4 = (const float4*)p.qp;
        float4 a = p4[tid], b4 = p4[256 + tid], c4 = p4[512 + tid], d4 = p4[768 + tid];
        float4 qv = {a.x + b4.x + c4.x + d4.x, a.y + b4.y + c4.y + d4.y,
                     a.z + b4.z + c4.z + d4.z, a.w + b4.w + c4.w + d4.w};
        qls[tid] = qv;
        __syncthreads();
        #pragma unroll
        for (int rr = 0; rr < 4; ++rr) {
            int row = b * 16 + wave * 4 + rr;
            const float4* W4 = (const float4*)(p.WK + (size_t)row * DK);
            float acc = 0.0f;
            #pragma unroll
            for (int i = 0; i < 4; ++i) {
                float4 w = W4[i * 64 + lane];
                float4 q = qls[i * 64 + lane];
                acc += w.x * q.x + w.y * q.y + w.z * q.z + w.w * q.w;
            }
            #pragma unroll
            for (int off = 32; off; off >>= 1) acc += __shfl_down(acc, off, 64);
            if (lane == 0) p.kq[row] = acc * (1.0f / 32.0f);
        }
    }
    grid.sync();

    // ---------------- P3: s[t] = sum_seg Dot[seg][idx] + pedot[t] ----------------
    {
        float* lkq  = smem;            // 4096
        float* lemb = smem + 4096;     // 18*257 = 4626
        float* lfrq = smem + 8768;     // 2048
        float* ldot = smem + 10816;    // 144
        float* lped = smem + 10960;    // 256
        for (int i = tid; i < 1024; i += 256)
            ((float4*)lkq)[i] = ((const float4*)p.kq)[i];
        for (int i = tid; i < 512; i += 256)
            ((float4*)lfrq)[i] = ((const float4*)p.freqt)[i];
        for (int i = tid; i < 4608; i += 256) {
            int row = i >> 8, r = i & 255;
            lemb[row * 257 + r] = (row < 9) ? p.o_emb[row * 256 + r]
                                            : p.d_emb[(row - 9) * 256 + r];
        }
        __syncthreads();
        if (tid < 144) {
            int seg = tid / 9, id = tid % 9;
            int base = (seg < 8) ? seg * 512 : (seg - 8) * 512 + 256;
            const float* e = lemb + ((seg < 8) ? id : (9 + id)) * 257;
            float a = 0.0f;
            for (int rr = 0; rr < 256; ++rr) {
                int r = (rr + seg * 4) & 255;
                a += e[r] * lkq[base + r];
            }
            ldot[tid] = 16.0f * a;
        }
        int tt = tid >> 4, sub = tid & 15;
        int t = b * 16 + tt;
        float acc = 0.0f;
        for (int jj = 0; jj < 128; ++jj) {
            int j = sub * 128 + ((jj + 2 * sub) & 127);
            float f = lfrq[j];
            float sv, cv;
            __sincosf((float)t * f, &sv, &cv);
            acc += sv * lkq[2 * j] + cv * lkq[2 * j + 1];
        }
        lped[tt * 16 + sub] = acc;
        __syncthreads();
        if (tid < 16) {
            int t2 = b * 16 + tid;
            float tot = 0.0f;
            #pragma unroll
            for (int i = 0; i < 16; ++i) tot += lped[tid * 16 + i];
            const uint32_t* ip = (const uint32_t*)(p.idxb + t2 * 16);
            uint32_t u0 = ip[0], u1 = ip[1], u2 = ip[2], u3 = ip[3];
            #pragma unroll
            for (int seg = 0; seg < 16; ++seg) {
                uint32_t u = (seg < 4) ? u0 : (seg < 8) ? u1 : (seg < 12) ? u2 : u3;
                int id = (u >> ((seg & 3) * 8)) & 0xFF;
                tot += ldot[seg * 9 + id];
            }
            p.s[t2] = tot;
        }
    }
    grid.sync();

    // ---------------- P4: fused softmax + hist(weight) + axpe ----------------
    {
        float* ls    = smem;           // 4096
        float* att_l = smem + 4096;    // 256 (this block's t-chunk)
        float* lh    = smem + 4352;    // 144
        float* red   = smem + 4512;    // 4
        float* bc    = smem + 4520;    // 2
        int C = b >> 4;                // t-chunk 0..15
        #pragma unroll
        for (int k = 0; k < 4; ++k)
            ((float4*)ls)[tid + 256 * k] = ((const float4*)p.s)[tid + 256 * k];
        if (tid < 144) lh[tid] = 0.0f;
        __syncthreads();
        float lm = -1e30f;
        #pragma unroll
        for (int k = 0; k < 16; ++k) lm = fmaxf(lm, ls[tid + 256 * k]);
        #pragma unroll
        for (int off = 32; off; off >>= 1) lm = fmaxf(lm, __shfl_down(lm, off, 64));
        if (lane == 0) red[wave] = lm;
        __syncthreads();
        if (tid == 0)
            bc[0] = fmaxf(fmaxf(red[0], red[1]), fmaxf(red[2], red[3]));
        __syncthreads();
        float m = bc[0];
        float lsum = 0.0f;
        #pragma unroll
        for (int k = 0; k < 16; ++k) lsum += expf(ls[tid + 256 * k] - m);
        #pragma unroll
        for (int off = 32; off; off >>= 1) lsum += __shfl_down(lsum, off, 64);
        if (lane == 0) red[wave] = lsum;
        __syncthreads();
        if (tid == 0) bc[1] = 1.0f / (red[0] + red[1] + red[2] + red[3]);
        __syncthreads();
        float invs = bc[1];
        att_l[tid] = expf(ls[C * 256 + tid] - m) * invs;
        __syncthreads();
        // hist: 16 t x 16 seg per block
        {
            int tl = tid >> 4, seg = tid & 15;
            int tg = b * 16 + tl;
            int id = p.idxb[tg * 16 + seg];
            atomicAdd(&lh[seg * 9 + id], att_l[((b & 15) << 4) + tl]);
        }
        __syncthreads();
        if (tid < 144) atomicAdd(&p.weight[tid], lh[tid]);
        // axpe: threads 0..127, one freq-pair each over this 256-t chunk
        if (tid < 128) {
            int j = ((b & 15) << 7) + tid;
            float f = p.freqt[j];
            float sf, cf;
            __sincosf(f, &sf, &cf);
            int t0 = C << 8;
            float ss = 0.f, sc = 0.f, sv = 0.f, cv = 0.f;
            for (int i = 0; i < 256; ++i) {
                if ((i & 63) == 0) __sincosf((float)(t0 + i) * f, &sv, &cv);
                float a = att_l[i];
                ss += a * sv; sc += a * cv;
                float ns = sv * cf + cv * sf;
                cv = cv * cf - sv * sf;
                sv = ns;
            }
            atomicAdd(&p.axpe[2 * j], ss);
            atomicAdd(&p.axpe[2 * j + 1], sc);
        }
    }
    grid.sync();

    // ---------------- P5: ctx[n] = ax·WV (blocks 0..127) ----------------
    if (b < 128) {
        float* lax = smem;
        int cc = b >> 2, nc = b & 3;
        if (tid < 128) {
            int c = cc * 128 + tid;
            int pl = c >> 9, rr = c & 511;
            int seg, r; const float* tab;
            if (rr < 256) { seg = pl;     r = rr;       tab = p.o_emb; }
            else          { seg = 8 + pl; r = rr - 256; tab = p.d_emb; }
            float a = 0.0f;
            #pragma unroll
            for (int id = 0; id < 9; ++id)
                a += p.weight[seg * 9 + id] * tab[id * 256 + r];
            lax[tid] = p.axpe[c] + 16.0f * a;
        }
        __syncthreads();
        int n = nc * 256 + tid;
        const float* Wp = p.WV + (size_t)cc * 128 * DK + n;
        float acc = 0.0f;
        for (int i = 0; i < 128; ++i)
            acc += lax[i] * Wp[(size_t)i * DK];
        atomicAdd(&p.ctx[n], acc);
    }
    grid.sync();

    // ---------------- P6: ol[m] = ctx·WO (blocks 0..63) ----------------
    if (b < 64) {
        float* lc = smem;
        int jc = b >> 2, mc = b & 3;
        if (tid < 64) lc[tid] = p.ctx[jc * 64 + tid];
        __syncthreads();
        int m = mc * 256 + tid;
        const float* Wp = p.WO + (size_t)jc * 64 * DK + m;
        float acc = 0.0f;
        for (int j = 0; j < 64; ++j)
            acc += lc[j] * Wp[(size_t)j * DK];
        atomicAdd(&p.ol[m], acc);
    }
    grid.sync();

    // ---------------- P7: heads (blocks 0..128) ----------------
    if (b < 129) {
        float* red = smem;
        const float* W; float bb;
        if (b < 64)       { W = p.Wo_pol + (size_t)b * DK;        bb = p.bo_pol[b]; }
        else if (b < 128) { W = p.Wd_pol + (size_t)(b - 64) * DK; bb = p.bd_pol[b - 64]; }
        else              { W = p.Wv;                              bb = p.bv[0]; }
        float s = 0.0f;
        for (int m = tid; m < DK; m += 256)
            s += fmaxf(p.ol[m], 0.0f) * W[m];
        #pragma unroll
        for (int off = 32; off; off >>= 1) s += __shfl_down(s, off, 64);
        if (lane == 0) red[wave] = s;
        __syncthreads();
        if (tid == 0) p.out[b] = red[0] + red[1] + red[2] + red[3] + bb;
    }
}

// =====================================================================
extern "C" void kernel_launch(void* const* d_in, const int* in_sizes, int n_in,
                              void* d_out, int out_size, void* d_ws, size_t ws_size,
                              hipStream_t stream) {
    char* ws = (char*)d_ws;
    Par prm;
    prm.obs    = (const int*)  d_in[0];
    prm.o_emb  = (const float*)d_in[1];
    prm.d_emb  = (const float*)d_in[2];
    prm.WQ     = (const float*)d_in[3];
    prm.WK     = (const float*)d_in[4];
    prm.WV     = (const float*)d_in[5];
    prm.WO     = (const float*)d_in[6];
    prm.Wo_pol = (const float*)d_in[7];
    prm.bo_pol = (const float*)d_in[8];
    prm.Wd_pol = (const float*)d_in[9];
    prm.bd_pol = (const float*)d_in[10];
    prm.Wv     = (const float*)d_in[11];
    prm.bv     = (const float*)d_in[12];
    prm.idxb   = (unsigned char*)(ws + IDX_OFF);
    prm.freqt  = (float*)(ws + FRQ_OFF);
    prm.kq     = (float*)(ws + KQ_OFF);
    prm.s      = (float*)(ws + S_OFF);
    prm.qp     = (float*)(ws + QP_OFF);
    prm.axpe   = (float*)(ws + AXPE_OFF);
    prm.weight = (float*)(ws + W_OFF);
    prm.ctx    = (float*)(ws + CTX_OFF);
    prm.ol     = (float*)(ws + OL_OFF);
    prm.out    = (float*)d_out;

    void* args[] = { &prm };
    hipLaunchCooperativeKernel((void*)mega_k, dim3(GRID), dim3(256), args, 0, stream);
}

// Round 6
// 171.622 us; speedup vs baseline: 2.1331x; 2.1331x over previous
//
#include <hip/hip_runtime.h>
#include <stdint.h>

// ---------- constants ----------
#define T_WIN   4096
#define DFULL   4096
#define DK      1024
#define LOG2_10000 13.287712379549449f

// ---------- workspace layout (bytes), non-overlapping ----------
static const size_t IDX_OFF  = 0;         // idxb [4096][16] uchar   = 65536
static const size_t FRQ_OFF  = 65536;     // freqt [2048] f          = 8192
static const size_t KQ_OFF   = 73728;     // kq    [4096] f          = 16384
static const size_t S_OFF    = 90112;     // s     [4096] f          = 16384
static const size_t PE16_OFF = 106496;    // pe16 [2048 j][16 tt] float2 = 262144
// ---- contiguous zero region: 10496 floats = 41984 B ----
static const size_t QP_OFF   = 368640;    // qp   [4][1024] f
static const size_t AXPE_OFF = 385024;    // axpe [4096] f
static const size_t W_OFF    = 401408;    // weight [144] f (pad 256)
static const size_t CTX_OFF  = 402432;    // ctx [1024] f
static const size_t OL_OFF   = 406528;    // ol  [1024] f
// end 410624

// =====================================================================
// K1 setup: blocks 0..255 idx extraction; block 256 zero+freq;
//           blocks 257..288 pe16 table (sin/cos of tt*f_j, small args)
// =====================================================================
__global__ void setup_k(const int* __restrict__ obs,
                        unsigned char* __restrict__ idxb,
                        float* __restrict__ freqt,
                        float2* __restrict__ pe16,
                        float* __restrict__ zbase) {
    int b = blockIdx.x, tid = threadIdx.x;
    if (b < 256) {
        int g = b * 256 + tid;               // obs row = t*16 + pl*2 + which
        const int* r = obs + (size_t)g * 9;
        int id = 0;
        #pragma unroll
        for (int j = 1; j < 9; ++j) id += j * r[j];
        int t = g >> 4, pl = (g >> 1) & 7, which = g & 1;
        idxb[t * 16 + which * 8 + pl] = (unsigned char)id;
    } else if (b == 256) {
        for (int i = tid; i < 10496; i += 256) zbase[i] = 0.0f;
        for (int i = tid; i < 2048; i += 256)
            freqt[i] = exp2f(-((float)(2 * i) * (1.0f / 4096.0f)) * LOG2_10000);
    } else {
        int e0 = (b - 257) * 1024 + tid * 4;
        #pragma unroll
        for (int k = 0; k < 4; ++k) {
            int e = e0 + k;                  // 0..32767
            int tt = e >> 11, j = e & 2047;
            float f = exp2f(-((float)(2 * j) * (1.0f / 4096.0f)) * LOG2_10000);
            float sv, cv;
            __sincosf((float)tt * f, &sv, &cv);
            pe16[j * 16 + tt] = {sv, cv};
        }
    }
}

// =====================================================================
// K2: q partials; block b = k-chunk of 16 rows, x derived from obs directly
// =====================================================================
__global__ void q_k(const int* __restrict__ obs,
                    const float* __restrict__ o_emb,
                    const float* __restrict__ d_emb,
                    const float* __restrict__ WQ,
                    float* __restrict__ qp) {
    __shared__ float lx[16];
    int b = blockIdx.x, tid = threadIdx.x;
    int kb = b * 16;
    int pl = kb >> 9, rr = kb & 511;
    const float* tab; int r0, which;
    if (rr < 256) { tab = o_emb; r0 = rr;       which = 0; }
    else          { tab = d_emb; r0 = rr - 256; which = 1; }
    if (tid < 16) {
        int row = 65520 + pl * 2 + which;     // t = 4095 rows
        const int* r = obs + (size_t)row * 9;
        int id = 0;
        #pragma unroll
        for (int j = 1; j < 9; ++j) id += j * r[j];
        int c = kb + tid;
        float f = exp2f(-((float)(c & ~1) * (1.0f / 4096.0f)) * LOG2_10000);
        float sv, cv;
        __sincosf(4095.0f * f, &sv, &cv);
        lx[tid] = tab[id * 256 + r0 + tid] * 16.0f + ((c & 1) ? cv : sv);
    }
    __syncthreads();
    const float4* W4 = (const float4*)WQ;
    float4 acc = {0.f, 0.f, 0.f, 0.f};
    #pragma unroll
    for (int k = 0; k < 16; ++k) {
        float xv = lx[k];
        float4 w = W4[(size_t)(kb + k) * 256 + tid];
        acc.x += xv * w.x; acc.y += xv * w.y;
        acc.z += xv * w.z; acc.w += xv * w.w;
    }
    float* dst = qp + (b >> 6) * 1024 + tid * 4;
    atomicAdd(dst + 0, acc.x);
    atomicAdd(dst + 1, acc.y);
    atomicAdd(dst + 2, acc.z);
    atomicAdd(dst + 3, acc.w);
}

// =====================================================================
// K3: kq[c] = (WK[c]·q)/32 ; q = sum of 4 partials. 4 rows per block.
// =====================================================================
__global__ void kq_k(const float* __restrict__ WK,
                     const float* __restrict__ qp,
                     float* __restrict__ kq) {
    __shared__ float4 qls[256];
    int tid = threadIdx.x;
    const float4* p4 = (const float4*)qp;
    float4 a = p4[tid], b4 = p4[256 + tid], c4 = p4[512 + tid], d4 = p4[768 + tid];
    qls[tid] = {a.x + b4.x + c4.x + d4.x, a.y + b4.y + c4.y + d4.y,
                a.z + b4.z + c4.z + d4.z, a.w + b4.w + c4.w + d4.w};
    __syncthreads();
    int wave = tid >> 6, lane = tid & 63;
    int cc = blockIdx.x * 4 + wave;
    const float4* W4 = (const float4*)(WK + (size_t)cc * DK);
    float acc = 0.0f;
    #pragma unroll
    for (int i = 0; i < 4; ++i) {
        float4 w = W4[i * 64 + lane];
        float4 q = qls[i * 64 + lane];
        acc += w.x * q.x + w.y * q.y + w.z * q.z + w.w * q.w;
    }
    #pragma unroll
    for (int off = 32; off; off >>= 1) acc += __shfl_down(acc, off, 64);
    if (lane == 0) kq[cc] = acc * (1.0f / 32.0f);
}

// =====================================================================
// K4: s[t] = sum_seg Dot[seg][idx] + pedot[t], t in [b*16, b*16+16)
// pedot via angle addition: anchor sincos(b*16*f_j) + pe16 table
// =====================================================================
__global__ __launch_bounds__(256) void scores_k(
        const float* __restrict__ kq,
        const float* __restrict__ o_emb, const float* __restrict__ d_emb,
        const float* __restrict__ freqt,
        const float2* __restrict__ pe16,
        const unsigned char* __restrict__ idxb,
        float* __restrict__ s) {
    __shared__ __align__(16) float lkq[4096];
    __shared__ __align__(16) float2 lanc[2048];
    __shared__ float lemb[18 * 257];
    __shared__ float ldot[144];
    __shared__ float lped[256];
    int tid = threadIdx.x, b = blockIdx.x;
    for (int i = tid; i < 1024; i += 256)
        ((float4*)lkq)[i] = ((const float4*)kq)[i];
    for (int i = tid; i < 4608; i += 256) {
        int row = i >> 8, r = i & 255;
        lemb[row * 257 + r] = (row < 9) ? o_emb[row * 256 + r]
                                        : d_emb[(row - 9) * 256 + r];
    }
    // anchors: sincos(b*16 * f_j), 8 j per thread
    {
        float base = (float)(b * 16);
        #pragma unroll
        for (int k = 0; k < 8; ++k) {
            int j = tid * 8 + k;
            float sv, cv;
            __sincosf(base * freqt[j], &sv, &cv);
            lanc[j] = {sv, cv};
        }
    }
    __syncthreads();
    if (tid < 144) {
        int seg = tid / 9, id = tid % 9;
        int base = (seg < 8) ? seg * 512 : (seg - 8) * 512 + 256;
        const float* e = lemb + ((seg < 8) ? id : (9 + id)) * 257;
        float a = 0.0f;
        for (int rr = 0; rr < 256; ++rr) {
            int r = (rr + seg * 4) & 255;
            a += e[r] * lkq[base + r];
        }
        ldot[tid] = 16.0f * a;
    }
    // pedot: thread (tt, sub); 128 j each via angle addition
    int tt = tid >> 4, sub = tid & 15;
    float acc = 0.0f;
    for (int jj = 0; jj < 128; ++jj) {
        int j = sub * 128 + ((jj + sub * 13) & 127);   // bank stagger
        float2 anc = lanc[j];
        float2 pt = pe16[j * 16 + tt];
        float sv = anc.x * pt.y + anc.y * pt.x;        // sin(A+B)
        float cv = anc.y * pt.y - anc.x * pt.x;        // cos(A+B)
        acc += sv * lkq[2 * j] + cv * lkq[2 * j + 1];
    }
    lped[tt * 16 + sub] = acc;
    __syncthreads();
    if (tid < 16) {
        int t2 = b * 16 + tid;
        float tot = 0.0f;
        #pragma unroll
        for (int i = 0; i < 16; ++i) tot += lped[tid * 16 + i];
        const uint32_t* ip = (const uint32_t*)(idxb + t2 * 16);
        uint32_t u0 = ip[0], u1 = ip[1], u2 = ip[2], u3 = ip[3];
        #pragma unroll
        for (int seg = 0; seg < 16; ++seg) {
            uint32_t u = (seg < 4) ? u0 : (seg < 8) ? u1 : (seg < 12) ? u2 : u3;
            int id = (u >> ((seg & 3) * 8)) & 0xFF;
            tot += ldot[seg * 9 + id];
        }
        s[t2] = tot;
    }
}

// =====================================================================
// K5: fused softmax + hist(weight) + axpe. grid 128.
// Each block recomputes softmax stats from s (bitwise identical).
// hist: t in [b*32, b*32+32). axpe: chunk C=b>>3, j in [(b&7)*256, +256)
// =====================================================================
__global__ void att_post_k(const float* __restrict__ s,
                           const float* __restrict__ freqt,
                           const unsigned char* __restrict__ idxb,
                           float* __restrict__ weight,
                           float* __restrict__ axpe) {
    __shared__ __align__(16) float ls[4096];
    __shared__ float att_l[256];
    __shared__ float lh[144];
    __shared__ float red[4];
    __shared__ float bc[2];
    int tid = threadIdx.x, b = blockIdx.x;
    int wave = tid >> 6, lane = tid & 63;
    int C = b >> 3;
    #pragma unroll
    for (int k = 0; k < 4; ++k)
        ((float4*)ls)[tid + 256 * k] = ((const float4*)s)[tid + 256 * k];
    if (tid < 144) lh[tid] = 0.0f;
    __syncthreads();
    float lm = -1e30f;
    #pragma unroll
    for (int k = 0; k < 16; ++k) lm = fmaxf(lm, ls[tid + 256 * k]);
    #pragma unroll
    for (int off = 32; off; off >>= 1) lm = fmaxf(lm, __shfl_down(lm, off, 64));
    if (lane == 0) red[wave] = lm;
    __syncthreads();
    if (tid == 0) bc[0] = fmaxf(fmaxf(red[0], red[1]), fmaxf(red[2], red[3]));
    __syncthreads();
    float m = bc[0];
    float lsum = 0.0f;
    #pragma unroll
    for (int k = 0; k < 16; ++k) lsum += expf(ls[tid + 256 * k] - m);
    #pragma unroll
    for (int off = 32; off; off >>= 1) lsum += __shfl_down(lsum, off, 64);
    if (lane == 0) red[wave] = lsum;
    __syncthreads();
    if (tid == 0) bc[1] = 1.0f / (red[0] + red[1] + red[2] + red[3]);
    __syncthreads();
    float inv = bc[1];
    att_l[tid] = expf(ls[C * 256 + tid] - m) * inv;
    // hist: 32 t x 16 seg
    #pragma unroll
    for (int i = 0; i < 2; ++i) {
        int it = tid + 256 * i;
        int tl = it >> 4, seg = it & 15;
        int t = b * 32 + tl;
        float av = expf(ls[t] - m) * inv;
        atomicAdd(&lh[seg * 9 + idxb[t * 16 + seg]], av);
    }
    __syncthreads();
    if (tid < 144) atomicAdd(&weight[tid], lh[tid]);
    // axpe: one freq pair per thread over this 256-t chunk
    {
        int j = (b & 7) * 256 + tid;
        float f = freqt[j];
        float sf, cf;
        __sincosf(f, &sf, &cf);
        int t0 = C << 8;
        float ss = 0.f, sc = 0.f, sv = 0.f, cv = 0.f;
        for (int i = 0; i < 256; ++i) {
            if ((i & 63) == 0) __sincosf((float)(t0 + i) * f, &sv, &cv);
            float a = att_l[i];
            ss += a * sv; sc += a * cv;
            float ns = sv * cf + cv * sf;
            cv = cv * cf - sv * sf;
            sv = ns;
        }
        atomicAdd(&axpe[2 * j], ss);
        atomicAdd(&axpe[2 * j + 1], sc);
    }
}

// =====================================================================
// K6: ctx[n] = sum_c ax[c]*WV[c][n]; ax built on the fly per c-chunk
// =====================================================================
__global__ void ctxv_k(const float* __restrict__ weight,
                       const float* __restrict__ axpe,
                       const float* __restrict__ o_emb,
                       const float* __restrict__ d_emb,
                       const float* __restrict__ WV,
                       float* __restrict__ ctx) {
    __shared__ float lax[128];
    int tid = threadIdx.x;
    int cc = blockIdx.x >> 2, nc = blockIdx.x & 3;
    if (tid < 128) {
        int c = cc * 128 + tid;
        int pl = c >> 9, rr = c & 511;
        int seg, r; const float* tab;
        if (rr < 256) { seg = pl;     r = rr;       tab = o_emb; }
        else          { seg = 8 + pl; r = rr - 256; tab = d_emb; }
        float a = 0.0f;
        #pragma unroll
        for (int id = 0; id < 9; ++id)
            a += weight[seg * 9 + id] * tab[id * 256 + r];
        lax[tid] = axpe[c] + 16.0f * a;
    }
    __syncthreads();
    int n = nc * 256 + tid;
    const float* Wp = WV + (size_t)cc * 128 * DK + n;
    float acc = 0.0f;
    for (int i = 0; i < 128; ++i)
        acc += lax[i] * Wp[(size_t)i * DK];
    atomicAdd(&ctx[n], acc);
}

// =====================================================================
// K7: ol[m] = sum_j ctx[j]*WO[j][m]
// =====================================================================
__global__ void olast_k(const float* __restrict__ ctx,
                        const float* __restrict__ WO,
                        float* __restrict__ ol) {
    __shared__ float lc[64];
    int tid = threadIdx.x;
    int jc = blockIdx.x >> 2, mc = blockIdx.x & 3;
    if (tid < 64) lc[tid] = ctx[jc * 64 + tid];
    __syncthreads();
    int m = mc * 256 + tid;
    const float* Wp = WO + (size_t)jc * 64 * DK + m;
    float acc = 0.0f;
    for (int j = 0; j < 64; ++j)
        acc += lc[j] * Wp[(size_t)j * DK];
    atomicAdd(&ol[m], acc);
}

// =====================================================================
// K8: heads
// =====================================================================
__global__ void heads_k(const float* __restrict__ ol,
                        const float* __restrict__ Wo_pol, const float* __restrict__ bo_pol,
                        const float* __restrict__ Wd_pol, const float* __restrict__ bd_pol,
                        const float* __restrict__ Wv,     const float* __restrict__ bv,
                        float* __restrict__ out) {
    __shared__ float red[4];
    int o = blockIdx.x;
    const float* W; float b;
    if (o < 64)       { W = Wo_pol + (size_t)o * DK;        b = bo_pol[o]; }
    else if (o < 128) { W = Wd_pol + (size_t)(o - 64) * DK; b = bd_pol[o - 64]; }
    else              { W = Wv;                              b = bv[0]; }
    float s = 0.0f;
    for (int m = threadIdx.x; m < DK; m += 256)
        s += fmaxf(ol[m], 0.0f) * W[m];
    #pragma unroll
    for (int off = 32; off; off >>= 1) s += __shfl_down(s, off, 64);
    int wave = threadIdx.x >> 6, lane = threadIdx.x & 63;
    if (lane == 0) red[wave] = s;
    __syncthreads();
    if (threadIdx.x == 0) out[o] = red[0] + red[1] + red[2] + red[3] + b;
}

// =====================================================================
extern "C" void kernel_launch(void* const* d_in, const int* in_sizes, int n_in,
                              void* d_out, int out_size, void* d_ws, size_t ws_size,
                              hipStream_t stream) {
    const int*   obs    = (const int*)  d_in[0];
    const float* o_emb  = (const float*)d_in[1];
    const float* d_emb  = (const float*)d_in[2];
    const float* WQ     = (const float*)d_in[3];
    const float* WK     = (const float*)d_in[4];
    const float* WV     = (const float*)d_in[5];
    const float* WO     = (const float*)d_in[6];
    const float* Wo_pol = (const float*)d_in[7];
    const float* bo_pol = (const float*)d_in[8];
    const float* Wd_pol = (const float*)d_in[9];
    const float* bd_pol = (const float*)d_in[10];
    const float* Wv     = (const float*)d_in[11];
    const float* bv     = (const float*)d_in[12];
    float* out = (float*)d_out;

    char* ws = (char*)d_ws;
    unsigned char* idxb = (unsigned char*)(ws + IDX_OFF);
    float*  freqt = (float*)(ws + FRQ_OFF);
    float*  kq    = (float*)(ws + KQ_OFF);
    float*  s     = (float*)(ws + S_OFF);
    float2* pe16  = (float2*)(ws + PE16_OFF);
    float*  qp    = (float*)(ws + QP_OFF);
    float*  axpe  = (float*)(ws + AXPE_OFF);
    float*  wgt   = (float*)(ws + W_OFF);
    float*  ctx   = (float*)(ws + CTX_OFF);
    float*  ol    = (float*)(ws + OL_OFF);

    setup_k<<<289, 256, 0, stream>>>(obs, idxb, freqt, pe16, qp);
    q_k<<<256, 256, 0, stream>>>(obs, o_emb, d_emb, WQ, qp);
    kq_k<<<1024, 256, 0, stream>>>(WK, qp, kq);
    scores_k<<<256, 256, 0, stream>>>(kq, o_emb, d_emb, freqt, pe16, idxb, s);
    att_post_k<<<128, 256, 0, stream>>>(s, freqt, idxb, wgt, axpe);
    ctxv_k<<<128, 256, 0, stream>>>(wgt, axpe, o_emb, d_emb, WV, ctx);
    olast_k<<<64, 256, 0, stream>>>(ctx, WO, ol);
    heads_k<<<129, 256, 0, stream>>>(ol, Wo_pol, bo_pol, Wd_pol, bd_pol, Wv, bv, out);
}